// Round 6
// baseline (21506.490 us; speedup 1.0000x reference)
//
#include <hip/hip_runtime.h>

#define NODES 32768
#define EDGES 524288
#define BGR   64
#define LSEQ  512
#define DEMB  256
#define HDIM  512

typedef unsigned short u16;
typedef unsigned int   u32;
typedef unsigned long long u64;
typedef __attribute__((ext_vector_type(8))) short short8;
typedef __attribute__((ext_vector_type(4))) float f32x4;

__device__ __forceinline__ float bf2f(u16 u){ u32 x = ((u32)u)<<16; float f; __builtin_memcpy(&f,&x,4); return f; }
__device__ __forceinline__ u16 f2bf(float f){ u32 x; __builtin_memcpy(&x,&f,4); u32 r = x + 0x7fffu + ((x>>16)&1u); return (u16)(r>>16); }
__device__ __forceinline__ float lo16(u32 u){ u32 x = u<<16; float f; __builtin_memcpy(&f,&x,4); return f; }
__device__ __forceinline__ float hi16(u32 u){ u32 x = u & 0xffff0000u; float f; __builtin_memcpy(&f,&x,4); return f; }
__device__ __forceinline__ u32 pack2(float a, float b){ return (u32)f2bf(a) | ((u32)f2bf(b)<<16); }

// ---------------- utility kernels ----------------

__global__ void zero_i32(int* p, int n){
  int i = blockIdx.x*256 + threadIdx.x;
  if (i < n) p[i] = 0;
}

// out[n*K + k] = bf16(in[k*N + n])   (in is [K][N] row-major)
__global__ void transpose_cast(const float* __restrict__ in, u16* __restrict__ out, int K, int N){
  int i = blockIdx.x*256 + threadIdx.x;
  if (i < N*K){ int n = i / K, k = i - n*K; out[i] = f2bf(in[(size_t)k*N + n]); }
}

__global__ void cast_bf(const float* __restrict__ in, u16* __restrict__ out, int n){
  int i = blockIdx.x*256 + threadIdx.x;
  if (i < n) out[i] = f2bf(in[i]);
}

__global__ void count_indeg(const int* __restrict__ dst, int* __restrict__ indeg){
  int e = blockIdx.x*256 + threadIdx.x;
  if (e < EDGES) atomicAdd(&indeg[dst[e]], 1);
}

__global__ void compute_dinv(const int* __restrict__ indeg, float* __restrict__ dinv){
  int i = blockIdx.x*256 + threadIdx.x;
  if (i < NODES) dinv[i] = rsqrtf((float)(indeg[i] + 1));  // +1 self loop
}

// single-block exclusive scan of indeg -> row_ptr (+cursor copy). N = 32768 = 1024*32
__global__ __launch_bounds__(1024) void scan_csr(const int* __restrict__ indeg,
                                                 int* __restrict__ row_ptr,
                                                 int* __restrict__ cursor){
  __shared__ int part[1024];
  int tid = threadIdx.x, base = tid*32;
  int loc[32]; int s = 0;
  for (int i=0;i<32;i++){ loc[i] = s; s += indeg[base+i]; }
  part[tid] = s; __syncthreads();
  for (int off=1; off<1024; off<<=1){
    int v = part[tid]; int add = (tid>=off) ? part[tid-off] : 0;
    __syncthreads(); part[tid] = v + add; __syncthreads();
  }
  int offt = (tid==0) ? 0 : part[tid-1];
  for (int i=0;i<32;i++){ int v = offt + loc[i]; row_ptr[base+i] = v; cursor[base+i] = v; }
}

__global__ void fill_csr(const int* __restrict__ src, const int* __restrict__ dst,
                         int* __restrict__ cursor, int* __restrict__ csr_src){
  int e = blockIdx.x*256 + threadIdx.x;
  if (e < EDGES){ int d = dst[e]; int p = atomicAdd(&cursor[d], 1); csr_src[p] = src[e]; }
}

// ---------------- GCN aggregation ----------------
__global__ __launch_bounds__(256) void agg_emb(const int* __restrict__ x, const u16* __restrict__ embb,
    const float* __restrict__ dinv, const int* __restrict__ row_ptr, const int* __restrict__ indeg,
    const int* __restrict__ csr_src, u16* __restrict__ out){
  int node = blockIdx.x*4 + (threadIdx.x>>6);
  int lane = threadIdx.x & 63;
  float di = dinv[node];
  int xi = x[node];
  u64 hv = *(const u64*)(embb + (size_t)xi*DEMB + lane*4);
  u32 h0 = (u32)hv, h1 = (u32)(hv>>32);
  float a0 = lo16(h0)*di, a1 = hi16(h0)*di, a2 = lo16(h1)*di, a3 = hi16(h1)*di;
  int st = row_ptr[node], cn = indeg[node];
  for (int p = st; p < st+cn; p++){
    int s = csr_src[p];
    float ws = dinv[s];
    u64 v = *(const u64*)(embb + (size_t)x[s]*DEMB + lane*4);
    u32 w0 = (u32)v, w1 = (u32)(v>>32);
    a0 += lo16(w0)*ws; a1 += hi16(w0)*ws; a2 += lo16(w1)*ws; a3 += hi16(w1)*ws;
  }
  u64 pv = (u64)pack2(a0*di,a1*di) | ((u64)pack2(a2*di,a3*di)<<32);
  *(u64*)(out + (size_t)node*DEMB + lane*4) = pv;
}

__global__ __launch_bounds__(256) void agg_h(const u16* __restrict__ hin, const float* __restrict__ dinv,
    const int* __restrict__ row_ptr, const int* __restrict__ indeg,
    const int* __restrict__ csr_src, u16* __restrict__ out){
  int node = blockIdx.x*4 + (threadIdx.x>>6);
  int lane = threadIdx.x & 63;
  float di = dinv[node];
  float a[8];
  uint4 hv = *((const uint4*)(hin + (size_t)node*HDIM) + lane);
  a[0]=lo16(hv.x)*di; a[1]=hi16(hv.x)*di; a[2]=lo16(hv.y)*di; a[3]=hi16(hv.y)*di;
  a[4]=lo16(hv.z)*di; a[5]=hi16(hv.z)*di; a[6]=lo16(hv.w)*di; a[7]=hi16(hv.w)*di;
  int st = row_ptr[node], cn = indeg[node];
  for (int p = st; p < st+cn; p++){
    int s = csr_src[p];
    float ws = dinv[s];
    uint4 v = *((const uint4*)(hin + (size_t)s*HDIM) + lane);
    a[0]+=lo16(v.x)*ws; a[1]+=hi16(v.x)*ws; a[2]+=lo16(v.y)*ws; a[3]+=hi16(v.y)*ws;
    a[4]+=lo16(v.z)*ws; a[5]+=hi16(v.z)*ws; a[6]+=lo16(v.w)*ws; a[7]+=hi16(v.w)*ws;
  }
  uint4 o; o.x=pack2(a[0]*di,a[1]*di); o.y=pack2(a[2]*di,a[3]*di);
  o.z=pack2(a[4]*di,a[5]*di); o.w=pack2(a[6]*di,a[7]*di);
  *(uint4*)(out + (size_t)node*HDIM + lane*8) = o;
}

// ---------------- bf16 MFMA GEMM: C[M,N] = act(A[M,K] @ BT[N,K]^T + bias) ----------------
#define BM 128
#define BN 128
#define BKK 32
__global__ __launch_bounds__(256) void gemm_bt(const u16* __restrict__ A, const u16* __restrict__ BT,
    const float* __restrict__ bias, u16* __restrict__ C, int M, int N, int K, int relu){
  __shared__ u16 aS[BM][BKK+8];
  __shared__ u16 bS[BN][BKK+8];
  int tid = threadIdx.x;
  int m0 = blockIdx.y * BM, n0 = blockIdx.x * BN;
  int lane = tid & 63, w = tid >> 6;
  int wm = w >> 1, wn = w & 1;
  f32x4 acc[4][4];
  for (int i=0;i<4;i++) for (int j=0;j<4;j++) acc[i][j] = (f32x4)0.0f;

  int r  = tid >> 1;
  int cc = (tid & 1) * 16;
  const u16* Ag = A + (size_t)(m0 + r) * K + cc;
  const u16* Bg = BT + (size_t)(n0 + r) * K + cc;
  int l15 = lane & 15, q8 = (lane >> 4) * 8;

  for (int k0 = 0; k0 < K; k0 += BKK) {
    uint4 av0 = *(const uint4*)(Ag + k0);
    uint4 av1 = *(const uint4*)(Ag + k0 + 8);
    uint4 bv0 = *(const uint4*)(Bg + k0);
    uint4 bv1 = *(const uint4*)(Bg + k0 + 8);
    *(uint4*)&aS[r][cc]   = av0; *(uint4*)&aS[r][cc+8] = av1;
    *(uint4*)&bS[r][cc]   = bv0; *(uint4*)&bS[r][cc+8] = bv1;
    __syncthreads();
    short8 af[4], bfr[4];
    for (int i=0;i<4;i++) af[i]  = *(const short8*)&aS[wm*64 + i*16 + l15][q8];
    for (int j=0;j<4;j++) bfr[j] = *(const short8*)&bS[wn*64 + j*16 + l15][q8];
    for (int i=0;i<4;i++)
      for (int j=0;j<4;j++)
        acc[i][j] = __builtin_amdgcn_mfma_f32_16x16x32_bf16(af[i], bfr[j], acc[i][j], 0, 0, 0);
    __syncthreads();
  }
  int q = lane >> 4;
  for (int i=0;i<4;i++) for (int j=0;j<4;j++){
    int col = n0 + wn*64 + j*16 + l15;
    float bval = bias[col];
    for (int rr=0; rr<4; rr++){
      int row = m0 + wm*64 + i*16 + q*4 + rr;
      float v = acc[i][j][rr] + bval;
      if (relu) v = fmaxf(v, 0.f);
      C[(size_t)row * N + col] = f2bf(v);
    }
  }
}

// ---------------- GRU: register-resident Whh, ONE workgroup per 16-graph group ----------------
// 4 WGs x 1024 threads (16 waves). Wave j holds B-fragments of its 96 gh-columns
// (3 gates x 2 16-col tiles, K=512 -> 6x16 short8 = 384 VGPRs) in registers for the whole
// sequence (Whh bf16 = 1.5 MB vs 2 MB VGPR file per CU -- LDS is too small, registers aren't).
// h is double-buffered in LDS (2 x 16x520 bf16); the cross-slice all-gather is ONE
// __syncthreads per step. Pointwise runs in MFMA C-layout registers (r/z/n tiles align
// lane-for-lane); h_prev and the running mean never leave registers. Zero inter-WG traffic.
__global__ __launch_bounds__(1024, 1) void gru_kernel(const u16* __restrict__ gi,
    const float* __restrict__ Whh, const float* __restrict__ bhh,
    float* __restrict__ graph_emb){
  __shared__ u16 h_lds[2][16*520];

  int tid = threadIdx.x;
  int g = blockIdx.x;           // 4 groups of 16 graphs
  int j = tid >> 6;             // wave = column slice
  int l = tid & 63;
  int l15 = l & 15, q = l >> 4;

  // ---- load weight fragments: B[tau][kc], tau = gate*2+half ----
  short8 B[6][16];
  #pragma unroll
  for (int gate = 0; gate < 3; gate++){
    #pragma unroll
    for (int half = 0; half < 2; half++){
      int c = gate*512 + j*32 + half*16 + l15;
      const float* wr = Whh + (size_t)c*512;
      #pragma unroll
      for (int kc = 0; kc < 16; kc++){
        f32x4 w0 = *(const f32x4*)(wr + kc*32 + q*8);
        f32x4 w1 = *(const f32x4*)(wr + kc*32 + q*8 + 4);
        short8 f;
        f[0]=(short)f2bf(w0[0]); f[1]=(short)f2bf(w0[1]); f[2]=(short)f2bf(w0[2]); f[3]=(short)f2bf(w0[3]);
        f[4]=(short)f2bf(w1[0]); f[5]=(short)f2bf(w1[1]); f[6]=(short)f2bf(w1[2]); f[7]=(short)f2bf(w1[3]);
        B[gate*2+half][kc] = f;
      }
    }
  }

  float bias[6];
  #pragma unroll
  for (int tau = 0; tau < 6; tau++){
    int gate = tau >> 1, half = tau & 1;
    bias[tau] = bhh[gate*512 + j*32 + half*16 + l15];
  }

  for (int i = tid; i < 16*520; i += 1024) h_lds[0][i] = 0;

  const u16* gi_g = gi + (size_t)g * 16 * 512 * 1536;
  float hp[2][4];    // h_prev in C-layout: [half-tile][rr]
  float am[2][4];    // mean accumulator
  #pragma unroll
  for (int th=0; th<2; th++) for (int rr=0; rr<4; rr++){ hp[th][rr]=0.f; am[th][rr]=0.f; }

  __syncthreads();

  for (int t = 0; t < LSEQ; t++){
    // gi prefetch in C-layout (overlaps the MFMA phase): b = q*4+rr, c = j*32+th*16+l15
    u16 gv[2][4][3];
    #pragma unroll
    for (int th=0; th<2; th++){
      #pragma unroll
      for (int rr=0; rr<4; rr++){
        int b = q*4 + rr;
        const u16* gp = gi_g + ((size_t)b*512 + t)*1536 + j*32 + th*16 + l15;
        gv[th][rr][0] = gp[0]; gv[th][rr][1] = gp[512]; gv[th][rr][2] = gp[1024];
      }
    }

    // MFMA phase: gh = h @ Whh^T for this wave's 96 cols
    const u16* hb = h_lds[t & 1];
    f32x4 acc[6];
    #pragma unroll
    for (int tau=0; tau<6; tau++) acc[tau] = (f32x4)0.0f;
    #pragma unroll
    for (int kc = 0; kc < 16; kc++){
      short8 a = *(const short8*)(hb + l15*520 + kc*32 + q*8);
      #pragma unroll
      for (int tau = 0; tau < 6; tau++)
        acc[tau] = __builtin_amdgcn_mfma_f32_16x16x32_bf16(a, B[tau][kc], acc[tau], 0, 0, 0);
    }

    // pointwise in C-layout; write h_new to the other h buffer
    u16* ho = h_lds[(t+1) & 1];
    #pragma unroll
    for (int th=0; th<2; th++){
      #pragma unroll
      for (int rr=0; rr<4; rr++){
        float ghr = acc[0+th][rr] + bias[0+th];
        float ghz = acc[2+th][rr] + bias[2+th];
        float ghn = acc[4+th][rr] + bias[4+th];
        float rg = 1.f / (1.f + __expf(-(bf2f(gv[th][rr][0]) + ghr)));
        float zg = 1.f / (1.f + __expf(-(bf2f(gv[th][rr][1]) + ghz)));
        float pre = bf2f(gv[th][rr][2]) + rg * ghn;
        pre = fminf(fmaxf(pre, -20.f), 20.f);
        float e2 = __expf(2.f * pre);
        float nn = (e2 - 1.f) / (e2 + 1.f);
        float h_new = (1.f - zg) * nn + zg * hp[th][rr];
        hp[th][rr] = h_new;
        am[th][rr] += h_new;
        int b = q*4 + rr;
        ho[b*520 + j*32 + th*16 + l15] = f2bf(h_new);
      }
    }
    __syncthreads();
  }

  #pragma unroll
  for (int th=0; th<2; th++){
    #pragma unroll
    for (int rr=0; rr<4; rr++){
      int b = q*4 + rr;
      graph_emb[(size_t)(g*16 + b)*512 + j*32 + th*16 + l15] = am[th][rr] * (1.f/512.f);
    }
  }
}

// ---------------- head: relu(g@fc1+b) @ fc2 + b -> sigmoid ----------------
__global__ __launch_bounds__(256) void head(const float* __restrict__ graph_emb, const float* __restrict__ focal,
    const float* __restrict__ fc1w, const float* __restrict__ fc1b,
    const float* __restrict__ fc2w, const float* __restrict__ fc2b, float* __restrict__ out){
  __shared__ float gv[513];
  __shared__ float h1s[512];
  __shared__ float red[4];
  int bq = blockIdx.x, tid = threadIdx.x;
  for (int i = tid; i < 512; i += 256) gv[i] = graph_emb[(size_t)bq*512 + i];
  if (tid == 0) gv[512] = focal[bq];
  __syncthreads();
  for (int c = tid; c < 512; c += 256){
    float acc = fc1b[c];
    for (int k = 0; k < 513; k++) acc += gv[k] * fc1w[(size_t)k*512 + c];
    h1s[c] = fmaxf(acc, 0.f);
  }
  __syncthreads();
  float p = h1s[tid]*fc2w[tid] + h1s[tid+256]*fc2w[tid+256];
  for (int off = 32; off; off >>= 1) p += __shfl_down(p, off, 64);
  if ((tid & 63) == 0) red[tid >> 6] = p;
  __syncthreads();
  if (tid == 0){
    float s = red[0]+red[1]+red[2]+red[3] + fc2b[0];
    out[bq] = 1.f / (1.f + __expf(-s));
  }
}

// ---------------- launch ----------------
extern "C" void kernel_launch(void* const* d_in, const int* in_sizes, int n_in,
                              void* d_out, int out_size, void* d_ws, size_t ws_size,
                              hipStream_t stream){
  const int*   x     = (const int*)d_in[0];
  const int*   edge  = (const int*)d_in[1];
  const int*   srcp  = edge;
  const int*   dstp  = edge + EDGES;
  const float* focal = (const float*)d_in[3];
  const float* emb   = (const float*)d_in[4];
  const float* W1    = (const float*)d_in[5];
  const float* b1    = (const float*)d_in[6];
  const float* W2    = (const float*)d_in[7];
  const float* b2    = (const float*)d_in[8];
  const float* Wih   = (const float*)d_in[9];
  const float* Whh   = (const float*)d_in[10];
  const float* bih   = (const float*)d_in[11];
  const float* bhh   = (const float*)d_in[12];
  const float* fc1w  = (const float*)d_in[13];
  const float* fc1b  = (const float*)d_in[14];
  const float* fc2w  = (const float*)d_in[15];
  const float* fc2b  = (const float*)d_in[16];

  char* ws = (char*)d_ws;
  constexpr size_t H2_OFF    = 0;                      // 32 MB
  constexpr size_t AGG1_OFF  = 33554432;               // 16 MB
  constexpr size_t H1_OFF    = 50331648;               // 32 MB
  constexpr size_t AGG2_OFF  = 83886080;               // 32 MB (embb lives here until agg_h)
  constexpr size_t GI_OFF    = 33554432;               // 96 MB (after aggs dead)
  constexpr size_t MISC      = 134217728;
  constexpr size_t INDEG_OFF = MISC;
  constexpr size_t DINV_OFF  = MISC + 131328;
  constexpr size_t ROWPTR_OFF= MISC + 262400;
  constexpr size_t CURSOR_OFF= MISC + 393472;
  constexpr size_t CSR_OFF   = MISC + 524544;
  constexpr size_t W1T_OFF   = MISC + 2621696;
  constexpr size_t W2T_OFF   = MISC + 2883840;
  constexpr size_t WIHB_OFF  = MISC + 3408128;
  constexpr size_t GEMB_OFF  = MISC + 5243136;

  int*   indeg  = (int*)(ws + INDEG_OFF);
  float* dinv   = (float*)(ws + DINV_OFF);
  int*   rowptr = (int*)(ws + ROWPTR_OFF);
  int*   cursor = (int*)(ws + CURSOR_OFF);
  int*   csrsrc = (int*)(ws + CSR_OFF);
  u16*   W1T    = (u16*)(ws + W1T_OFF);
  u16*   W2T    = (u16*)(ws + W2T_OFF);
  u16*   WihB   = (u16*)(ws + WIHB_OFF);
  u16*   agg1   = (u16*)(ws + AGG1_OFF);
  u16*   h1     = (u16*)(ws + H1_OFF);
  u16*   agg2   = (u16*)(ws + AGG2_OFF);
  u16*   embb   = (u16*)(ws + AGG2_OFF);               // dead before agg_h writes agg2
  u16*   h2     = (u16*)(ws + H2_OFF);
  u16*   gi     = (u16*)(ws + GI_OFF);
  float* gemb   = (float*)(ws + GEMB_OFF);

  zero_i32<<<129, 256, 0, stream>>>(indeg, 32768 + 64);
  transpose_cast<<<512, 256, 0, stream>>>(W1, W1T, 256, 512);
  transpose_cast<<<1024, 256, 0, stream>>>(W2, W2T, 512, 512);
  cast_bf<<<3072, 256, 0, stream>>>(Wih, WihB, 1536*512);
  cast_bf<<<10000, 256, 0, stream>>>(emb, embb, 10000*256);
  count_indeg<<<2048, 256, 0, stream>>>(dstp, indeg);
  compute_dinv<<<128, 256, 0, stream>>>(indeg, dinv);
  scan_csr<<<1, 1024, 0, stream>>>(indeg, rowptr, cursor);
  fill_csr<<<2048, 256, 0, stream>>>(srcp, dstp, cursor, csrsrc);
  agg_emb<<<8192, 256, 0, stream>>>(x, embb, dinv, rowptr, indeg, csrsrc, agg1);
  gemm_bt<<<dim3(4, 256), 256, 0, stream>>>(agg1, W1T, b1, h1, NODES, 512, 256, 1);
  agg_h<<<8192, 256, 0, stream>>>(h1, dinv, rowptr, indeg, csrsrc, agg2);
  gemm_bt<<<dim3(4, 256), 256, 0, stream>>>(agg2, W2T, b2, h2, NODES, 512, 512, 1);
  gemm_bt<<<dim3(12, 256), 256, 0, stream>>>(h2, WihB, bih, gi, NODES, 1536, 512, 0);
  gru_kernel<<<4, 1024, 0, stream>>>(gi, Whh, bhh, gemb);
  head<<<64, 256, 0, stream>>>(gemb, focal, fc1w, fc1b, fc2w, fc2b, (float*)d_out);
}

// Round 7
// 2729.360 us; speedup vs baseline: 7.8797x; 7.8797x over previous
//
#include <hip/hip_runtime.h>

#define NODES 32768
#define EDGES 524288
#define BGR   64
#define LSEQ  512
#define DEMB  256
#define HDIM  512

typedef unsigned short u16;
typedef unsigned int   u32;
typedef unsigned long long u64;
typedef __attribute__((ext_vector_type(8))) short short8;
typedef __attribute__((ext_vector_type(4))) float f32x4;

__device__ __forceinline__ float bf2f(u16 u){ u32 x = ((u32)u)<<16; float f; __builtin_memcpy(&f,&x,4); return f; }
__device__ __forceinline__ u16 f2bf(float f){ u32 x; __builtin_memcpy(&x,&f,4); u32 r = x + 0x7fffu + ((x>>16)&1u); return (u16)(r>>16); }
__device__ __forceinline__ float lo16(u32 u){ u32 x = u<<16; float f; __builtin_memcpy(&f,&x,4); return f; }
__device__ __forceinline__ float hi16(u32 u){ u32 x = u & 0xffff0000u; float f; __builtin_memcpy(&f,&x,4); return f; }
__device__ __forceinline__ u32 pack2(float a, float b){ return (u32)f2bf(a) | ((u32)f2bf(b)<<16); }

// ---------------- utility kernels ----------------

__global__ void zero_i32(int* p, int n){
  int i = blockIdx.x*256 + threadIdx.x;
  if (i < n) p[i] = 0;
}

// out[n*K + k] = bf16(in[k*N + n])   (in is [K][N] row-major)
__global__ void transpose_cast(const float* __restrict__ in, u16* __restrict__ out, int K, int N){
  int i = blockIdx.x*256 + threadIdx.x;
  if (i < N*K){ int n = i / K, k = i - n*K; out[i] = f2bf(in[(size_t)k*N + n]); }
}

__global__ void cast_bf(const float* __restrict__ in, u16* __restrict__ out, int n){
  int i = blockIdx.x*256 + threadIdx.x;
  if (i < n) out[i] = f2bf(in[i]);
}

__global__ void count_indeg(const int* __restrict__ dst, int* __restrict__ indeg){
  int e = blockIdx.x*256 + threadIdx.x;
  if (e < EDGES) atomicAdd(&indeg[dst[e]], 1);
}

__global__ void compute_dinv(const int* __restrict__ indeg, float* __restrict__ dinv){
  int i = blockIdx.x*256 + threadIdx.x;
  if (i < NODES) dinv[i] = rsqrtf((float)(indeg[i] + 1));  // +1 self loop
}

// single-block exclusive scan of indeg -> row_ptr (+cursor copy). N = 32768 = 1024*32
__global__ __launch_bounds__(1024) void scan_csr(const int* __restrict__ indeg,
                                                 int* __restrict__ row_ptr,
                                                 int* __restrict__ cursor){
  __shared__ int part[1024];
  int tid = threadIdx.x, base = tid*32;
  int loc[32]; int s = 0;
  for (int i=0;i<32;i++){ loc[i] = s; s += indeg[base+i]; }
  part[tid] = s; __syncthreads();
  for (int off=1; off<1024; off<<=1){
    int v = part[tid]; int add = (tid>=off) ? part[tid-off] : 0;
    __syncthreads(); part[tid] = v + add; __syncthreads();
  }
  int offt = (tid==0) ? 0 : part[tid-1];
  for (int i=0;i<32;i++){ int v = offt + loc[i]; row_ptr[base+i] = v; cursor[base+i] = v; }
}

__global__ void fill_csr(const int* __restrict__ src, const int* __restrict__ dst,
                         int* __restrict__ cursor, int* __restrict__ csr_src){
  int e = blockIdx.x*256 + threadIdx.x;
  if (e < EDGES){ int d = dst[e]; int p = atomicAdd(&cursor[d], 1); csr_src[p] = src[e]; }
}

// ---------------- GCN aggregation ----------------
__global__ __launch_bounds__(256) void agg_emb(const int* __restrict__ x, const u16* __restrict__ embb,
    const float* __restrict__ dinv, const int* __restrict__ row_ptr, const int* __restrict__ indeg,
    const int* __restrict__ csr_src, u16* __restrict__ out){
  int node = blockIdx.x*4 + (threadIdx.x>>6);
  int lane = threadIdx.x & 63;
  float di = dinv[node];
  int xi = x[node];
  u64 hv = *(const u64*)(embb + (size_t)xi*DEMB + lane*4);
  u32 h0 = (u32)hv, h1 = (u32)(hv>>32);
  float a0 = lo16(h0)*di, a1 = hi16(h0)*di, a2 = lo16(h1)*di, a3 = hi16(h1)*di;
  int st = row_ptr[node], cn = indeg[node];
  for (int p = st; p < st+cn; p++){
    int s = csr_src[p];
    float ws = dinv[s];
    u64 v = *(const u64*)(embb + (size_t)x[s]*DEMB + lane*4);
    u32 w0 = (u32)v, w1 = (u32)(v>>32);
    a0 += lo16(w0)*ws; a1 += hi16(w0)*ws; a2 += lo16(w1)*ws; a3 += hi16(w1)*ws;
  }
  u64 pv = (u64)pack2(a0*di,a1*di) | ((u64)pack2(a2*di,a3*di)<<32);
  *(u64*)(out + (size_t)node*DEMB + lane*4) = pv;
}

__global__ __launch_bounds__(256) void agg_h(const u16* __restrict__ hin, const float* __restrict__ dinv,
    const int* __restrict__ row_ptr, const int* __restrict__ indeg,
    const int* __restrict__ csr_src, u16* __restrict__ out){
  int node = blockIdx.x*4 + (threadIdx.x>>6);
  int lane = threadIdx.x & 63;
  float di = dinv[node];
  float a[8];
  uint4 hv = *((const uint4*)(hin + (size_t)node*HDIM) + lane);
  a[0]=lo16(hv.x)*di; a[1]=hi16(hv.x)*di; a[2]=lo16(hv.y)*di; a[3]=hi16(hv.y)*di;
  a[4]=lo16(hv.z)*di; a[5]=hi16(hv.z)*di; a[6]=lo16(hv.w)*di; a[7]=hi16(hv.w)*di;
  int st = row_ptr[node], cn = indeg[node];
  for (int p = st; p < st+cn; p++){
    int s = csr_src[p];
    float ws = dinv[s];
    uint4 v = *((const uint4*)(hin + (size_t)s*HDIM) + lane);
    a[0]+=lo16(v.x)*ws; a[1]+=hi16(v.x)*ws; a[2]+=lo16(v.y)*ws; a[3]+=hi16(v.y)*ws;
    a[4]+=lo16(v.z)*ws; a[5]+=hi16(v.z)*ws; a[6]+=lo16(v.w)*ws; a[7]+=hi16(v.w)*ws;
  }
  uint4 o; o.x=pack2(a[0]*di,a[1]*di); o.y=pack2(a[2]*di,a[3]*di);
  o.z=pack2(a[4]*di,a[5]*di); o.w=pack2(a[6]*di,a[7]*di);
  *(uint4*)(out + (size_t)node*HDIM + lane*8) = o;
}

// ---------------- bf16 MFMA GEMM: C[M,N] = act(A[M,K] @ BT[N,K]^T + bias) ----------------
#define BM 128
#define BN 128
#define BKK 32
__global__ __launch_bounds__(256) void gemm_bt(const u16* __restrict__ A, const u16* __restrict__ BT,
    const float* __restrict__ bias, u16* __restrict__ C, int M, int N, int K, int relu){
  __shared__ u16 aS[BM][BKK+8];
  __shared__ u16 bS[BN][BKK+8];
  int tid = threadIdx.x;
  int m0 = blockIdx.y * BM, n0 = blockIdx.x * BN;
  int lane = tid & 63, w = tid >> 6;
  int wm = w >> 1, wn = w & 1;
  f32x4 acc[4][4];
  for (int i=0;i<4;i++) for (int j=0;j<4;j++) acc[i][j] = (f32x4)0.0f;

  int r  = tid >> 1;
  int cc = (tid & 1) * 16;
  const u16* Ag = A + (size_t)(m0 + r) * K + cc;
  const u16* Bg = BT + (size_t)(n0 + r) * K + cc;
  int l15 = lane & 15, q8 = (lane >> 4) * 8;

  for (int k0 = 0; k0 < K; k0 += BKK) {
    uint4 av0 = *(const uint4*)(Ag + k0);
    uint4 av1 = *(const uint4*)(Ag + k0 + 8);
    uint4 bv0 = *(const uint4*)(Bg + k0);
    uint4 bv1 = *(const uint4*)(Bg + k0 + 8);
    *(uint4*)&aS[r][cc]   = av0; *(uint4*)&aS[r][cc+8] = av1;
    *(uint4*)&bS[r][cc]   = bv0; *(uint4*)&bS[r][cc+8] = bv1;
    __syncthreads();
    short8 af[4], bfr[4];
    for (int i=0;i<4;i++) af[i]  = *(const short8*)&aS[wm*64 + i*16 + l15][q8];
    for (int j=0;j<4;j++) bfr[j] = *(const short8*)&bS[wn*64 + j*16 + l15][q8];
    for (int i=0;i<4;i++)
      for (int j=0;j<4;j++)
        acc[i][j] = __builtin_amdgcn_mfma_f32_16x16x32_bf16(af[i], bfr[j], acc[i][j], 0, 0, 0);
    __syncthreads();
  }
  int q = lane >> 4;
  for (int i=0;i<4;i++) for (int j=0;j<4;j++){
    int col = n0 + wn*64 + j*16 + l15;
    float bval = bias[col];
    for (int rr=0; rr<4; rr++){
      int row = m0 + wm*64 + i*16 + q*4 + rr;
      float v = acc[i][j][rr] + bval;
      if (relu) v = fmaxf(v, 0.f);
      C[(size_t)row * N + col] = f2bf(v);
    }
  }
}

// ---------------- GRU: 4 groups x 16 WGs; WG j owns 32-wide H-slice ----------------
// Protocol = R5 (tag-in-data, relaxed agent atomics, proven): publish u64 ((t+1)<<32|bf16pair),
// poll own 8 u64, 2-deep parity. R7 changes (no protocol change, no hang modes):
//  (1) LANE-ORDER SWIZZLED fragment LDS: slot16B(kc,lane) at offset kc*65+lane (pad 65 de-aliases
//      banks). R5's stride-520 reads were 8-way bank conflicts (2.9e7 SQ_LDS_BANK_CONFLICT,
//      ~885 cy/step/WG); lane-linear b128 reads are conflict-free.
//  (2) gi gate prefetch 2 steps deep (~8us slack vs ~1.4us): cold-HBM latency off the chain.
__global__ __launch_bounds__(512) void gru_kernel(const u16* __restrict__ gi,
    const float* __restrict__ Whh, const float* __restrict__ bhh,
    float* __restrict__ graph_emb, u64* __restrict__ xbuf){
  __shared__ __align__(16) u16 w_swz[6*16*65*8];     // 99840 B: [tile w][kc][lane] 16B frags
  __shared__ __align__(16) u16 h_swz[2][16*65*8];    // 2x16640 B: [kc][lane] 16B frags
  __shared__ float gh_lds[16*100];

  int tid = threadIdx.x;
  int g = blockIdx.x >> 4, j = blockIdx.x & 15;
  int lane = tid & 63, wave = tid >> 6;
  int l15 = lane & 15, qr = (lane>>4)*4;

  // ---- load Whh slice into swizzled LDS: frag(w,kc,lane): row=lane&15, qq=lane>>4
  //      source col c = gate*512 + j*32 + half*16 + row, k = kc*32 + qq*8 ----
  for (int s = tid; s < 6144; s += 512){
    int w = s >> 10, rem = s & 1023, kc = rem >> 6, l = rem & 63;
    int row = l & 15, qq = l >> 4;
    int gate = w >> 1, half = w & 1;
    int c = gate*512 + j*32 + half*16 + row;
    const float* srcp = Whh + (size_t)c*512 + kc*32 + qq*8;
    u16* dst = w_swz + ((size_t)(w*16 + kc)*65 + l)*8;
    #pragma unroll
    for (int i2 = 0; i2 < 8; i2++) dst[i2] = f2bf(srcp[i2]);
  }
  for (int i2 = tid; i2 < 16*65*8; i2 += 512) h_swz[0][i2] = 0;

  int b = tid >> 5, hh = tid & 31;     // (batch-in-group, h-in-slice)
  int bg = g*16 + b;
  int c_r = j*32 + hh, c_z = 512 + j*32 + hh, c_n = 1024 + j*32 + hh;
  float bias_r = bhh[c_r], bias_z = bhh[c_z], bias_n = bhh[c_n];
  const u16* gi_row = gi + (size_t)bg * LSEQ * 1536;
  float h_prev = 0.f, accm = 0.f;

  u64* xb = xbuf + (size_t)g * 8192;   // [parity][16 b][256 slots] u64

  // 2-deep gate-input pipeline: gr0 = step t, gr1 = step t+1
  u16 gr0 = gi_row[c_r], gz0 = gi_row[c_z], gn0 = gi_row[c_n];
  const u16* gp1 = gi_row + 1536;
  u16 gr1 = gp1[c_r], gz1 = gp1[c_z], gn1 = gp1[c_n];

  // commit bases (u32 units) into swizzled h: thread (b,hh) holds dims [hh*16,hh*16+16) of row b
  int kcc = hh >> 1, qa = (hh & 1) * 2;
  int cb0 = (kcc*65 + (qa  )*16 + b) * 4;
  int cb1 = (kcc*65 + (qa+1)*16 + b) * 4;

  __syncthreads();

  for (int t = 0; t < LSEQ; t++){
    // prefetch t+2 at iter top (max slack; consumed 2 iters later)
    int tn = (t + 2 < LSEQ) ? t + 2 : t;
    const u16* gp2 = gi_row + (size_t)tn * 1536;
    u16 nr = gp2[c_r], nz = gp2[c_z], nn2 = gp2[c_n];

    if (wave < 6){
      const u16* hb = h_swz[t & 1];
      const u16* wb = w_swz + (size_t)wave*16*65*8;
      f32x4 acc0 = (f32x4)0.0f, acc1 = (f32x4)0.0f;
      #pragma unroll
      for (int kc = 0; kc < 8; kc++){
        acc0 = __builtin_amdgcn_mfma_f32_16x16x32_bf16(
                 *(const short8*)(hb + ((size_t)kc*65 + lane)*8),
                 *(const short8*)(wb + ((size_t)kc*65 + lane)*8), acc0, 0, 0, 0);
        acc1 = __builtin_amdgcn_mfma_f32_16x16x32_bf16(
                 *(const short8*)(hb + ((size_t)(kc+8)*65 + lane)*8),
                 *(const short8*)(wb + ((size_t)(kc+8)*65 + lane)*8), acc1, 0, 0, 0);
      }
      f32x4 acc = acc0 + acc1;
      int col = wave*16 + l15;
      #pragma unroll
      for (int rr2 = 0; rr2 < 4; rr2++) gh_lds[(qr + rr2)*100 + col] = acc[rr2];
    }
    __syncthreads();

    float ghr = gh_lds[b*100 + hh]      + bias_r;
    float ghz = gh_lds[b*100 + 32 + hh] + bias_z;
    float ghn = gh_lds[b*100 + 64 + hh] + bias_n;
    float rg = 1.f / (1.f + __expf(-(bf2f(gr0) + ghr)));
    float zg = 1.f / (1.f + __expf(-(bf2f(gz0) + ghz)));
    float pre = bf2f(gn0) + rg * ghn;
    pre = fminf(fmaxf(pre, -20.f), 20.f);
    float e2 = __expf(2.f * pre);
    float nn = (e2 - 1.f) / (e2 + 1.f);
    float h_new = (1.f - zg) * nn + zg * h_prev;
    accm += h_new; h_prev = h_new;

    u32 tag = (u32)(t + 1);
    // publish: tagged u64, relaxed agent-scope atomic store (fire-and-forget)
    float h_nb = __shfl_xor(h_new, 1, 64);   // partner hh^1 (same wave: lane^1)
    if ((hh & 1) == 0){
      u64 val = ((u64)tag << 32) | (u64)pack2(h_new, h_nb);
      __hip_atomic_store(xb + (size_t)((t&1)*16 + b)*256 + j*16 + (hh>>1), val,
                         __ATOMIC_RELAXED, __HIP_MEMORY_SCOPE_AGENT);
    }

    // poll own 8 tagged u64 (dims [hh*16,hh*16+16) of row b) — detection IS the refill
    const u64* rp = xb + (size_t)((t&1)*16 + b)*256 + hh*8;
    u64 v[8];
    bool ok;
    do {
      #pragma unroll
      for (int i=0;i<8;i++) v[i] = __hip_atomic_load(rp + i, __ATOMIC_RELAXED, __HIP_MEMORY_SCOPE_AGENT);
      ok = true;
      #pragma unroll
      for (int i=0;i<8;i++) ok = ok && ((u32)(v[i] >> 32) == tag);
    } while (!ok);

    // commit into swizzled h (parity t+1): frag (kc=hh/2, qq=qa+{0,1}, row=b)
    u32* hl = (u32*)h_swz[(t+1) & 1];
    uint4 w0; w0.x = (u32)v[0]; w0.y = (u32)v[1]; w0.z = (u32)v[2]; w0.w = (u32)v[3];
    uint4 w1; w1.x = (u32)v[4]; w1.y = (u32)v[5]; w1.z = (u32)v[6]; w1.w = (u32)v[7];
    *(uint4*)(hl + cb0) = w0;
    *(uint4*)(hl + cb1) = w1;
    __syncthreads();

    gr0 = gr1; gz0 = gz1; gn0 = gn1;
    gr1 = nr;  gz1 = nz;  gn1 = nn2;
  }
  graph_emb[(size_t)bg*512 + j*32 + hh] = accm * (1.f/512.f);
}

// ---------------- head: relu(g@fc1+b) @ fc2 + b -> sigmoid ----------------
__global__ __launch_bounds__(256) void head(const float* __restrict__ graph_emb, const float* __restrict__ focal,
    const float* __restrict__ fc1w, const float* __restrict__ fc1b,
    const float* __restrict__ fc2w, const float* __restrict__ fc2b, float* __restrict__ out){
  __shared__ float gv[513];
  __shared__ float h1s[512];
  __shared__ float red[4];
  int bq = blockIdx.x, tid = threadIdx.x;
  for (int i = tid; i < 512; i += 256) gv[i] = graph_emb[(size_t)bq*512 + i];
  if (tid == 0) gv[512] = focal[bq];
  __syncthreads();
  for (int c = tid; c < 512; c += 256){
    float acc = fc1b[c];
    for (int k = 0; k < 513; k++) acc += gv[k] * fc1w[(size_t)k*512 + c];
    h1s[c] = fmaxf(acc, 0.f);
  }
  __syncthreads();
  float p = h1s[tid]*fc2w[tid] + h1s[tid+256]*fc2w[tid+256];
  for (int off = 32; off; off >>= 1) p += __shfl_down(p, off, 64);
  if ((tid & 63) == 0) red[tid >> 6] = p;
  __syncthreads();
  if (tid == 0){
    float s = red[0]+red[1]+red[2]+red[3] + fc2b[0];
    out[bq] = 1.f / (1.f + __expf(-s));
  }
}

// ---------------- launch ----------------
extern "C" void kernel_launch(void* const* d_in, const int* in_sizes, int n_in,
                              void* d_out, int out_size, void* d_ws, size_t ws_size,
                              hipStream_t stream){
  const int*   x     = (const int*)d_in[0];
  const int*   edge  = (const int*)d_in[1];
  const int*   srcp  = edge;
  const int*   dstp  = edge + EDGES;
  const float* focal = (const float*)d_in[3];
  const float* emb   = (const float*)d_in[4];
  const float* W1    = (const float*)d_in[5];
  const float* b1    = (const float*)d_in[6];
  const float* W2    = (const float*)d_in[7];
  const float* b2    = (const float*)d_in[8];
  const float* Wih   = (const float*)d_in[9];
  const float* Whh   = (const float*)d_in[10];
  const float* bih   = (const float*)d_in[11];
  const float* bhh   = (const float*)d_in[12];
  const float* fc1w  = (const float*)d_in[13];
  const float* fc1b  = (const float*)d_in[14];
  const float* fc2w  = (const float*)d_in[15];
  const float* fc2b  = (const float*)d_in[16];

  char* ws = (char*)d_ws;
  constexpr size_t H2_OFF    = 0;                      // 32 MB
  constexpr size_t AGG1_OFF  = 33554432;               // 16 MB
  constexpr size_t H1_OFF    = 50331648;               // 32 MB
  constexpr size_t AGG2_OFF  = 83886080;               // 32 MB (embb lives here until agg_h)
  constexpr size_t GI_OFF    = 33554432;               // 96 MB (after aggs dead)
  constexpr size_t MISC      = 134217728;
  constexpr size_t INDEG_OFF = MISC;
  constexpr size_t DINV_OFF  = MISC + 131328;
  constexpr size_t ROWPTR_OFF= MISC + 262400;
  constexpr size_t CURSOR_OFF= MISC + 393472;
  constexpr size_t CSR_OFF   = MISC + 524544;
  constexpr size_t W1T_OFF   = MISC + 2621696;
  constexpr size_t W2T_OFF   = MISC + 2883840;
  constexpr size_t WIHB_OFF  = MISC + 3408128;
  constexpr size_t XBUF_OFF  = MISC + 4980992;         // 4 groups x 8192 u64 = 256 KB
  constexpr size_t GEMB_OFF  = MISC + 5243136;

  int*   indeg  = (int*)(ws + INDEG_OFF);
  float* dinv   = (float*)(ws + DINV_OFF);
  int*   rowptr = (int*)(ws + ROWPTR_OFF);
  int*   cursor = (int*)(ws + CURSOR_OFF);
  int*   csrsrc = (int*)(ws + CSR_OFF);
  u16*   W1T    = (u16*)(ws + W1T_OFF);
  u16*   W2T    = (u16*)(ws + W2T_OFF);
  u16*   WihB   = (u16*)(ws + WIHB_OFF);
  u16*   agg1   = (u16*)(ws + AGG1_OFF);
  u16*   h1     = (u16*)(ws + H1_OFF);
  u16*   agg2   = (u16*)(ws + AGG2_OFF);
  u16*   embb   = (u16*)(ws + AGG2_OFF);               // dead before agg_h writes agg2
  u16*   h2     = (u16*)(ws + H2_OFF);
  u16*   gi     = (u16*)(ws + GI_OFF);
  u64*   xbuf   = (u64*)(ws + XBUF_OFF);
  float* gemb   = (float*)(ws + GEMB_OFF);

  zero_i32<<<129, 256, 0, stream>>>(indeg, 32768 + 64);
  transpose_cast<<<512, 256, 0, stream>>>(W1, W1T, 256, 512);
  transpose_cast<<<1024, 256, 0, stream>>>(W2, W2T, 512, 512);
  cast_bf<<<3072, 256, 0, stream>>>(Wih, WihB, 1536*512);
  cast_bf<<<10000, 256, 0, stream>>>(emb, embb, 10000*256);
  count_indeg<<<2048, 256, 0, stream>>>(dstp, indeg);
  compute_dinv<<<128, 256, 0, stream>>>(indeg, dinv);
  scan_csr<<<1, 1024, 0, stream>>>(indeg, rowptr, cursor);
  fill_csr<<<2048, 256, 0, stream>>>(srcp, dstp, cursor, csrsrc);
  agg_emb<<<8192, 256, 0, stream>>>(x, embb, dinv, rowptr, indeg, csrsrc, agg1);
  gemm_bt<<<dim3(4, 256), 256, 0, stream>>>(agg1, W1T, b1, h1, NODES, 512, 256, 1);
  agg_h<<<8192, 256, 0, stream>>>(h1, dinv, rowptr, indeg, csrsrc, agg2);
  gemm_bt<<<dim3(4, 256), 256, 0, stream>>>(agg2, W2T, b2, h2, NODES, 512, 512, 1);
  gemm_bt<<<dim3(12, 256), 256, 0, stream>>>(h2, WihB, bih, gi, NODES, 1536, 512, 0);
  gru_kernel<<<64, 512, 0, stream>>>(gi, Whh, bhh, gemb, xbuf);
  head<<<64, 256, 0, stream>>>(gemb, focal, fc1w, fc1b, fc2w, fc2b, (float*)d_out);
}

// Round 8
// 2720.756 us; speedup vs baseline: 7.9046x; 1.0032x over previous
//
#include <hip/hip_runtime.h>

#define NODES 32768
#define EDGES 524288
#define BGR   64
#define LSEQ  512
#define DEMB  256
#define HDIM  512

typedef unsigned short u16;
typedef unsigned int   u32;
typedef unsigned long long u64;
typedef __attribute__((ext_vector_type(8))) short short8;
typedef __attribute__((ext_vector_type(4))) float f32x4;

__device__ __forceinline__ float bf2f(u16 u){ u32 x = ((u32)u)<<16; float f; __builtin_memcpy(&f,&x,4); return f; }
__device__ __forceinline__ u16 f2bf(float f){ u32 x; __builtin_memcpy(&x,&f,4); u32 r = x + 0x7fffu + ((x>>16)&1u); return (u16)(r>>16); }
__device__ __forceinline__ float lo16(u32 u){ u32 x = u<<16; float f; __builtin_memcpy(&f,&x,4); return f; }
__device__ __forceinline__ float hi16(u32 u){ u32 x = u & 0xffff0000u; float f; __builtin_memcpy(&f,&x,4); return f; }
__device__ __forceinline__ u32 pack2(float a, float b){ return (u32)f2bf(a) | ((u32)f2bf(b)<<16); }

// ---------------- utility kernels ----------------

__global__ void zero_i32(int* p, int n){
  int i = blockIdx.x*256 + threadIdx.x;
  if (i < n) p[i] = 0;
}

// out[n*K + k] = bf16(in[k*N + n])   (in is [K][N] row-major)
__global__ void transpose_cast(const float* __restrict__ in, u16* __restrict__ out, int K, int N){
  int i = blockIdx.x*256 + threadIdx.x;
  if (i < N*K){ int n = i / K, k = i - n*K; out[i] = f2bf(in[(size_t)k*N + n]); }
}

__global__ void cast_bf(const float* __restrict__ in, u16* __restrict__ out, int n){
  int i = blockIdx.x*256 + threadIdx.x;
  if (i < n) out[i] = f2bf(in[i]);
}

__global__ void count_indeg(const int* __restrict__ dst, int* __restrict__ indeg){
  int e = blockIdx.x*256 + threadIdx.x;
  if (e < EDGES) atomicAdd(&indeg[dst[e]], 1);
}

__global__ void compute_dinv(const int* __restrict__ indeg, float* __restrict__ dinv){
  int i = blockIdx.x*256 + threadIdx.x;
  if (i < NODES) dinv[i] = rsqrtf((float)(indeg[i] + 1));  // +1 self loop
}

// single-block exclusive scan of indeg -> row_ptr (+cursor copy). N = 32768 = 1024*32
__global__ __launch_bounds__(1024) void scan_csr(const int* __restrict__ indeg,
                                                 int* __restrict__ row_ptr,
                                                 int* __restrict__ cursor){
  __shared__ int part[1024];
  int tid = threadIdx.x, base = tid*32;
  int loc[32]; int s = 0;
  for (int i=0;i<32;i++){ loc[i] = s; s += indeg[base+i]; }
  part[tid] = s; __syncthreads();
  for (int off=1; off<1024; off<<=1){
    int v = part[tid]; int add = (tid>=off) ? part[tid-off] : 0;
    __syncthreads(); part[tid] = v + add; __syncthreads();
  }
  int offt = (tid==0) ? 0 : part[tid-1];
  for (int i=0;i<32;i++){ int v = offt + loc[i]; row_ptr[base+i] = v; cursor[base+i] = v; }
}

__global__ void fill_csr(const int* __restrict__ src, const int* __restrict__ dst,
                         int* __restrict__ cursor, int* __restrict__ csr_src){
  int e = blockIdx.x*256 + threadIdx.x;
  if (e < EDGES){ int d = dst[e]; int p = atomicAdd(&cursor[d], 1); csr_src[p] = src[e]; }
}

// ---------------- GCN aggregation ----------------
__global__ __launch_bounds__(256) void agg_emb(const int* __restrict__ x, const u16* __restrict__ embb,
    const float* __restrict__ dinv, const int* __restrict__ row_ptr, const int* __restrict__ indeg,
    const int* __restrict__ csr_src, u16* __restrict__ out){
  int node = blockIdx.x*4 + (threadIdx.x>>6);
  int lane = threadIdx.x & 63;
  float di = dinv[node];
  int xi = x[node];
  u64 hv = *(const u64*)(embb + (size_t)xi*DEMB + lane*4);
  u32 h0 = (u32)hv, h1 = (u32)(hv>>32);
  float a0 = lo16(h0)*di, a1 = hi16(h0)*di, a2 = lo16(h1)*di, a3 = hi16(h1)*di;
  int st = row_ptr[node], cn = indeg[node];
  for (int p = st; p < st+cn; p++){
    int s = csr_src[p];
    float ws = dinv[s];
    u64 v = *(const u64*)(embb + (size_t)x[s]*DEMB + lane*4);
    u32 w0 = (u32)v, w1 = (u32)(v>>32);
    a0 += lo16(w0)*ws; a1 += hi16(w0)*ws; a2 += lo16(w1)*ws; a3 += hi16(w1)*ws;
  }
  u64 pv = (u64)pack2(a0*di,a1*di) | ((u64)pack2(a2*di,a3*di)<<32);
  *(u64*)(out + (size_t)node*DEMB + lane*4) = pv;
}

__global__ __launch_bounds__(256) void agg_h(const u16* __restrict__ hin, const float* __restrict__ dinv,
    const int* __restrict__ row_ptr, const int* __restrict__ indeg,
    const int* __restrict__ csr_src, u16* __restrict__ out){
  int node = blockIdx.x*4 + (threadIdx.x>>6);
  int lane = threadIdx.x & 63;
  float di = dinv[node];
  float a[8];
  uint4 hv = *((const uint4*)(hin + (size_t)node*HDIM) + lane);
  a[0]=lo16(hv.x)*di; a[1]=hi16(hv.x)*di; a[2]=lo16(hv.y)*di; a[3]=hi16(hv.y)*di;
  a[4]=lo16(hv.z)*di; a[5]=hi16(hv.z)*di; a[6]=lo16(hv.w)*di; a[7]=hi16(hv.w)*di;
  int st = row_ptr[node], cn = indeg[node];
  for (int p = st; p < st+cn; p++){
    int s = csr_src[p];
    float ws = dinv[s];
    uint4 v = *((const uint4*)(hin + (size_t)s*HDIM) + lane);
    a[0]+=lo16(v.x)*ws; a[1]+=hi16(v.x)*ws; a[2]+=lo16(v.y)*ws; a[3]+=hi16(v.y)*ws;
    a[4]+=lo16(v.z)*ws; a[5]+=hi16(v.z)*ws; a[6]+=lo16(v.w)*ws; a[7]+=hi16(v.w)*ws;
  }
  uint4 o; o.x=pack2(a[0]*di,a[1]*di); o.y=pack2(a[2]*di,a[3]*di);
  o.z=pack2(a[4]*di,a[5]*di); o.w=pack2(a[6]*di,a[7]*di);
  *(uint4*)(out + (size_t)node*HDIM + lane*8) = o;
}

// ---------------- bf16 MFMA GEMM: C[M,N] = act(A[M,K] @ BT[N,K]^T + bias) ----------------
#define BM 128
#define BN 128
#define BKK 32
__global__ __launch_bounds__(256) void gemm_bt(const u16* __restrict__ A, const u16* __restrict__ BT,
    const float* __restrict__ bias, u16* __restrict__ C, int M, int N, int K, int relu){
  __shared__ u16 aS[BM][BKK+8];
  __shared__ u16 bS[BN][BKK+8];
  int tid = threadIdx.x;
  int m0 = blockIdx.y * BM, n0 = blockIdx.x * BN;
  int lane = tid & 63, w = tid >> 6;
  int wm = w >> 1, wn = w & 1;
  f32x4 acc[4][4];
  for (int i=0;i<4;i++) for (int j=0;j<4;j++) acc[i][j] = (f32x4)0.0f;

  int r  = tid >> 1;
  int cc = (tid & 1) * 16;
  const u16* Ag = A + (size_t)(m0 + r) * K + cc;
  const u16* Bg = BT + (size_t)(n0 + r) * K + cc;
  int l15 = lane & 15, q8 = (lane >> 4) * 8;

  for (int k0 = 0; k0 < K; k0 += BKK) {
    uint4 av0 = *(const uint4*)(Ag + k0);
    uint4 av1 = *(const uint4*)(Ag + k0 + 8);
    uint4 bv0 = *(const uint4*)(Bg + k0);
    uint4 bv1 = *(const uint4*)(Bg + k0 + 8);
    *(uint4*)&aS[r][cc]   = av0; *(uint4*)&aS[r][cc+8] = av1;
    *(uint4*)&bS[r][cc]   = bv0; *(uint4*)&bS[r][cc+8] = bv1;
    __syncthreads();
    short8 af[4], bfr[4];
    for (int i=0;i<4;i++) af[i]  = *(const short8*)&aS[wm*64 + i*16 + l15][q8];
    for (int j=0;j<4;j++) bfr[j] = *(const short8*)&bS[wn*64 + j*16 + l15][q8];
    for (int i=0;i<4;i++)
      for (int j=0;j<4;j++)
        acc[i][j] = __builtin_amdgcn_mfma_f32_16x16x32_bf16(af[i], bfr[j], acc[i][j], 0, 0, 0);
    __syncthreads();
  }
  int q = lane >> 4;
  for (int i=0;i<4;i++) for (int j=0;j<4;j++){
    int col = n0 + wn*64 + j*16 + l15;
    float bval = bias[col];
    for (int rr=0; rr<4; rr++){
      int row = m0 + wm*64 + i*16 + q*4 + rr;
      float v = acc[i][j][rr] + bval;
      if (relu) v = fmaxf(v, 0.f);
      C[(size_t)row * N + col] = f2bf(v);
    }
  }
}

// ---------------- GRU: 4 groups x 16 WGs; WG j owns 32-wide H-slice ----------------
// R8 sync protocol: FLAG-BASED. R5-R7's full-fat poll (2048 thr x 64 B spinning on a 16 KB
// region at the coherence point) was itself the congestion (~250 MB of poll FETCH traffic).
// Now: payload = untagged u32 bf16-pairs (half the bytes). Producer: publish 16 u32/row ->
// s_waitcnt vmcnt(0) (all payload acked at coherence point) -> barrier -> tid0 stores ONE
// flag u32 (value t+1) into flg[g][parity][j]. Consumer: wave 0 polls the 16 flags (ONE 64 B
// line) with a ballot loop -> barrier -> each thread does one batched 8xu32 agent load ->
// commit to swizzled LDS. Skew<=1 step (inductive via flags), 2-deep parity, poison
// 0xAAAAAAAA != tags 1..512, monotonic tags kill ABA. Same liveness shape as R5 (proven).
__global__ __launch_bounds__(512) void gru_kernel(const u16* __restrict__ gi,
    const float* __restrict__ Whh, const float* __restrict__ bhh,
    float* __restrict__ graph_emb, u32* __restrict__ xpay, u32* __restrict__ flg){
  __shared__ __align__(16) u16 w_swz[6*16*65*8];     // 99840 B: [tile w][kc][lane] 16B frags
  __shared__ __align__(16) u16 h_swz[2][16*65*8];    // 2x16640 B: [kc][lane] 16B frags
  __shared__ float gh_lds[16*100];

  int tid = threadIdx.x;
  int g = blockIdx.x >> 4, j = blockIdx.x & 15;
  int lane = tid & 63, wave = tid >> 6;
  int l15 = lane & 15, qr = (lane>>4)*4;

  // ---- load Whh slice into swizzled LDS ----
  for (int s = tid; s < 6144; s += 512){
    int w = s >> 10, rem = s & 1023, kc = rem >> 6, l = rem & 63;
    int row = l & 15, qq = l >> 4;
    int gate = w >> 1, half = w & 1;
    int c = gate*512 + j*32 + half*16 + row;
    const float* srcp = Whh + (size_t)c*512 + kc*32 + qq*8;
    u16* dst = w_swz + ((size_t)(w*16 + kc)*65 + l)*8;
    #pragma unroll
    for (int i2 = 0; i2 < 8; i2++) dst[i2] = f2bf(srcp[i2]);
  }
  for (int i2 = tid; i2 < 16*65*8; i2 += 512) h_swz[0][i2] = 0;

  int b = tid >> 5, hh = tid & 31;     // (batch-in-group, h-in-slice)
  int bg = g*16 + b;
  int c_r = j*32 + hh, c_z = 512 + j*32 + hh, c_n = 1024 + j*32 + hh;
  float bias_r = bhh[c_r], bias_z = bhh[c_z], bias_n = bhh[c_n];
  const u16* gi_row = gi + (size_t)bg * LSEQ * 1536;
  float h_prev = 0.f, accm = 0.f;

  // 2-deep gate-input pipeline: gr0 = step t, gr1 = step t+1
  u16 gr0 = gi_row[c_r], gz0 = gi_row[c_z], gn0 = gi_row[c_n];
  const u16* gp1 = gi_row + 1536;
  u16 gr1 = gp1[c_r], gz1 = gp1[c_z], gn1 = gp1[c_n];

  // commit bases (u32 units) into swizzled h
  int kcc = hh >> 1, qa = (hh & 1) * 2;
  int cb0 = (kcc*65 + (qa  )*16 + b) * 4;
  int cb1 = (kcc*65 + (qa+1)*16 + b) * 4;

  __syncthreads();

  for (int t = 0; t < LSEQ; t++){
    // prefetch t+2 at iter top (max slack; consumed 2 iters later)
    int tn = (t + 2 < LSEQ) ? t + 2 : t;
    const u16* gp2 = gi_row + (size_t)tn * 1536;
    u16 nr = gp2[c_r], nz = gp2[c_z], nn2 = gp2[c_n];

    if (wave < 6){
      const u16* hb = h_swz[t & 1];
      const u16* wb = w_swz + (size_t)wave*16*65*8;
      f32x4 acc0 = (f32x4)0.0f, acc1 = (f32x4)0.0f;
      #pragma unroll
      for (int kc = 0; kc < 8; kc++){
        acc0 = __builtin_amdgcn_mfma_f32_16x16x32_bf16(
                 *(const short8*)(hb + ((size_t)kc*65 + lane)*8),
                 *(const short8*)(wb + ((size_t)kc*65 + lane)*8), acc0, 0, 0, 0);
        acc1 = __builtin_amdgcn_mfma_f32_16x16x32_bf16(
                 *(const short8*)(hb + ((size_t)(kc+8)*65 + lane)*8),
                 *(const short8*)(wb + ((size_t)(kc+8)*65 + lane)*8), acc1, 0, 0, 0);
      }
      f32x4 acc = acc0 + acc1;
      int col = wave*16 + l15;
      #pragma unroll
      for (int rr2 = 0; rr2 < 4; rr2++) gh_lds[(qr + rr2)*100 + col] = acc[rr2];
    }
    __syncthreads();

    float ghr = gh_lds[b*100 + hh]      + bias_r;
    float ghz = gh_lds[b*100 + 32 + hh] + bias_z;
    float ghn = gh_lds[b*100 + 64 + hh] + bias_n;
    float rg = 1.f / (1.f + __expf(-(bf2f(gr0) + ghr)));
    float zg = 1.f / (1.f + __expf(-(bf2f(gz0) + ghz)));
    float pre = bf2f(gn0) + rg * ghn;
    pre = fminf(fmaxf(pre, -20.f), 20.f);
    float e2 = __expf(2.f * pre);
    float nn = (e2 - 1.f) / (e2 + 1.f);
    float h_new = (1.f - zg) * nn + zg * h_prev;
    accm += h_new; h_prev = h_new;

    u32 tag = (u32)(t + 1);
    int par = t & 1;

    // publish payload: bf16 pair as u32, relaxed agent-scope atomic store
    float h_nb = __shfl_xor(h_new, 1, 64);   // partner hh^1 (same wave: lane^1)
    if ((hh & 1) == 0){
      u32 pv = pack2(h_new, h_nb);
      __hip_atomic_store(xpay + (size_t)((g*2 + par)*16 + b)*256 + j*16 + (hh>>1), pv,
                         __ATOMIC_RELAXED, __HIP_MEMORY_SCOPE_AGENT);
    }
    asm volatile("s_waitcnt vmcnt(0)" ::: "memory");  // payload acked at coherence point
    __syncthreads();
    if (tid == 0)
      __hip_atomic_store(flg + (g*2 + par)*16 + j, tag,
                         __ATOMIC_RELAXED, __HIP_MEMORY_SCOPE_AGENT);

    // wave 0 polls the 16 flags (one 64 B line); everyone else waits at the barrier
    if (tid < 64){
      const u32* fp = flg + (g*2 + par)*16;
      bool ok;
      do {
        u32 f = (lane < 16)
              ? __hip_atomic_load(fp + lane, __ATOMIC_RELAXED, __HIP_MEMORY_SCOPE_AGENT)
              : tag;
        ok = (f == tag);
      } while (__ballot(ok) != 0xFFFFFFFFFFFFFFFFull);
    }
    __syncthreads();

    // bulk load payload: 8 u32 (32 B) per thread, one pipelined round trip
    const u32* rp = xpay + (size_t)((g*2 + par)*16 + b)*256 + hh*8;
    u32 v[8];
    #pragma unroll
    for (int i=0;i<8;i++) v[i] = __hip_atomic_load(rp + i, __ATOMIC_RELAXED, __HIP_MEMORY_SCOPE_AGENT);

    // commit into swizzled h (parity t+1)
    u32* hl = (u32*)h_swz[(t+1) & 1];
    uint4 w0; w0.x = v[0]; w0.y = v[1]; w0.z = v[2]; w0.w = v[3];
    uint4 w1; w1.x = v[4]; w1.y = v[5]; w1.z = v[6]; w1.w = v[7];
    *(uint4*)(hl + cb0) = w0;
    *(uint4*)(hl + cb1) = w1;
    __syncthreads();

    gr0 = gr1; gz0 = gz1; gn0 = gn1;
    gr1 = nr;  gz1 = nz;  gn1 = nn2;
  }
  graph_emb[(size_t)bg*512 + j*32 + hh] = accm * (1.f/512.f);
}

// ---------------- head: relu(g@fc1+b) @ fc2 + b -> sigmoid ----------------
__global__ __launch_bounds__(256) void head(const float* __restrict__ graph_emb, const float* __restrict__ focal,
    const float* __restrict__ fc1w, const float* __restrict__ fc1b,
    const float* __restrict__ fc2w, const float* __restrict__ fc2b, float* __restrict__ out){
  __shared__ float gv[513];
  __shared__ float h1s[512];
  __shared__ float red[4];
  int bq = blockIdx.x, tid = threadIdx.x;
  for (int i = tid; i < 512; i += 256) gv[i] = graph_emb[(size_t)bq*512 + i];
  if (tid == 0) gv[512] = focal[bq];
  __syncthreads();
  for (int c = tid; c < 512; c += 256){
    float acc = fc1b[c];
    for (int k = 0; k < 513; k++) acc += gv[k] * fc1w[(size_t)k*512 + c];
    h1s[c] = fmaxf(acc, 0.f);
  }
  __syncthreads();
  float p = h1s[tid]*fc2w[tid] + h1s[tid+256]*fc2w[tid+256];
  for (int off = 32; off; off >>= 1) p += __shfl_down(p, off, 64);
  if ((tid & 63) == 0) red[tid >> 6] = p;
  __syncthreads();
  if (tid == 0){
    float s = red[0]+red[1]+red[2]+red[3] + fc2b[0];
    out[bq] = 1.f / (1.f + __expf(-s));
  }
}

// ---------------- launch ----------------
extern "C" void kernel_launch(void* const* d_in, const int* in_sizes, int n_in,
                              void* d_out, int out_size, void* d_ws, size_t ws_size,
                              hipStream_t stream){
  const int*   x     = (const int*)d_in[0];
  const int*   edge  = (const int*)d_in[1];
  const int*   srcp  = edge;
  const int*   dstp  = edge + EDGES;
  const float* focal = (const float*)d_in[3];
  const float* emb   = (const float*)d_in[4];
  const float* W1    = (const float*)d_in[5];
  const float* b1    = (const float*)d_in[6];
  const float* W2    = (const float*)d_in[7];
  const float* b2    = (const float*)d_in[8];
  const float* Wih   = (const float*)d_in[9];
  const float* Whh   = (const float*)d_in[10];
  const float* bih   = (const float*)d_in[11];
  const float* bhh   = (const float*)d_in[12];
  const float* fc1w  = (const float*)d_in[13];
  const float* fc1b  = (const float*)d_in[14];
  const float* fc2w  = (const float*)d_in[15];
  const float* fc2b  = (const float*)d_in[16];

  char* ws = (char*)d_ws;
  constexpr size_t H2_OFF    = 0;                      // 32 MB
  constexpr size_t AGG1_OFF  = 33554432;               // 16 MB
  constexpr size_t H1_OFF    = 50331648;               // 32 MB
  constexpr size_t AGG2_OFF  = 83886080;               // 32 MB (embb lives here until agg_h)
  constexpr size_t GI_OFF    = 33554432;               // 96 MB (after aggs dead)
  constexpr size_t MISC      = 134217728;
  constexpr size_t INDEG_OFF = MISC;
  constexpr size_t DINV_OFF  = MISC + 131328;
  constexpr size_t ROWPTR_OFF= MISC + 262400;
  constexpr size_t CURSOR_OFF= MISC + 393472;
  constexpr size_t CSR_OFF   = MISC + 524544;
  constexpr size_t W1T_OFF   = MISC + 2621696;
  constexpr size_t W2T_OFF   = MISC + 2883840;
  constexpr size_t WIHB_OFF  = MISC + 3408128;
  constexpr size_t XPAY_OFF  = MISC + 4980992;         // 4 groups x 2 par x 16 x 256 u32 = 128 KB
  constexpr size_t FLG_OFF   = MISC + 5112064;         // 4 x 2 x 16 u32 = 512 B (poison-safe)
  constexpr size_t GEMB_OFF  = MISC + 5243136;

  int*   indeg  = (int*)(ws + INDEG_OFF);
  float* dinv   = (float*)(ws + DINV_OFF);
  int*   rowptr = (int*)(ws + ROWPTR_OFF);
  int*   cursor = (int*)(ws + CURSOR_OFF);
  int*   csrsrc = (int*)(ws + CSR_OFF);
  u16*   W1T    = (u16*)(ws + W1T_OFF);
  u16*   W2T    = (u16*)(ws + W2T_OFF);
  u16*   WihB   = (u16*)(ws + WIHB_OFF);
  u16*   agg1   = (u16*)(ws + AGG1_OFF);
  u16*   h1     = (u16*)(ws + H1_OFF);
  u16*   agg2   = (u16*)(ws + AGG2_OFF);
  u16*   embb   = (u16*)(ws + AGG2_OFF);               // dead before agg_h writes agg2
  u16*   h2     = (u16*)(ws + H2_OFF);
  u16*   gi     = (u16*)(ws + GI_OFF);
  u32*   xpay   = (u32*)(ws + XPAY_OFF);
  u32*   flg    = (u32*)(ws + FLG_OFF);
  float* gemb   = (float*)(ws + GEMB_OFF);

  zero_i32<<<129, 256, 0, stream>>>(indeg, 32768 + 64);
  transpose_cast<<<512, 256, 0, stream>>>(W1, W1T, 256, 512);
  transpose_cast<<<1024, 256, 0, stream>>>(W2, W2T, 512, 512);
  cast_bf<<<3072, 256, 0, stream>>>(Wih, WihB, 1536*512);
  cast_bf<<<10000, 256, 0, stream>>>(emb, embb, 10000*256);
  count_indeg<<<2048, 256, 0, stream>>>(dstp, indeg);
  compute_dinv<<<128, 256, 0, stream>>>(indeg, dinv);
  scan_csr<<<1, 1024, 0, stream>>>(indeg, rowptr, cursor);
  fill_csr<<<2048, 256, 0, stream>>>(srcp, dstp, cursor, csrsrc);
  agg_emb<<<8192, 256, 0, stream>>>(x, embb, dinv, rowptr, indeg, csrsrc, agg1);
  gemm_bt<<<dim3(4, 256), 256, 0, stream>>>(agg1, W1T, b1, h1, NODES, 512, 256, 1);
  agg_h<<<8192, 256, 0, stream>>>(h1, dinv, rowptr, indeg, csrsrc, agg2);
  gemm_bt<<<dim3(4, 256), 256, 0, stream>>>(agg2, W2T, b2, h2, NODES, 512, 512, 1);
  gemm_bt<<<dim3(12, 256), 256, 0, stream>>>(h2, WihB, bih, gi, NODES, 1536, 512, 0);
  gru_kernel<<<64, 512, 0, stream>>>(gi, Whh, bhh, gemb, xpay, flg);
  head<<<64, 256, 0, stream>>>(gemb, focal, fc1w, fc1b, fc2w, fc2b, (float*)d_out);
}